// Round 8
// baseline (1877.612 us; speedup 1.0000x reference)
//
#include <hip/hip_runtime.h>
#include <hip/hip_bf16.h>
#include <stdint.h>

#define N_ROWS 4096
#define DIM 512
#define M_COLS 50000
#define GTOT (M_COLS/16)   // 3125 column-groups of 16
#define SPLITS 16
#define TOPK 10

typedef __attribute__((ext_vector_type(8))) short bf16x8;
typedef __attribute__((ext_vector_type(4))) float f32x4;

__device__ __forceinline__ float waveSum(float v){
  #pragma unroll
  for (int off=32; off>0; off>>=1) v += __shfl_xor(v, off, 64);
  return v;
}

__device__ __forceinline__ unsigned short f2bf(float x){
  __hip_bfloat16 h = __float2bfloat16(x);
  return *reinterpret_cast<unsigned short*>(&h);
}

// row-wise L2 normalize f32 -> bf16, one row per block, 128 threads x float4
__global__ __launch_bounds__(128) void norm_bf16_kernel(const float* __restrict__ in,
                                                        unsigned short* __restrict__ out){
  const int row = blockIdx.x;
  const int t = threadIdx.x;
  const float4 v = *reinterpret_cast<const float4*>(in + (size_t)row*DIM + t*4);
  float ss = v.x*v.x + v.y*v.y + v.z*v.z + v.w*v.w;
  ss = waveSum(ss);
  __shared__ float sred[2];
  if ((t & 63) == 0) sred[t>>6] = ss;
  __syncthreads();
  const float r = rsqrtf(sred[0] + sred[1]);
  ushort4 o;
  o.x = f2bf(v.x*r); o.y = f2bf(v.y*r); o.z = f2bf(v.z*r); o.w = f2bf(v.w*r);
  *reinterpret_cast<ushort4*>(out + (size_t)row*DIM + t*4) = o;
}

// per-row: S += (x.y)/(|x||y|); also writes normalized X as bf16
__global__ __launch_bounds__(128) void dotS_kernel(const float* __restrict__ X, const float* __restrict__ Y,
                                                   unsigned short* __restrict__ srcb, float* __restrict__ S_acc){
  const int row = blockIdx.x;
  const int t = threadIdx.x;
  const float4 x = *reinterpret_cast<const float4*>(X + (size_t)row*DIM + t*4);
  const float4 y = *reinterpret_cast<const float4*>(Y + (size_t)row*DIM + t*4);
  float ssx = x.x*x.x+x.y*x.y+x.z*x.z+x.w*x.w;
  float ssy = y.x*y.x+y.y*y.y+y.z*y.z+y.w*y.w;
  float sxy = x.x*y.x+x.y*y.y+x.z*y.z+x.w*y.w;
  ssx = waveSum(ssx); ssy = waveSum(ssy); sxy = waveSum(sxy);
  __shared__ float r0[2], r1[2], r2[2];
  if ((t&63)==0){ r0[t>>6]=ssx; r1[t>>6]=ssy; r2[t>>6]=sxy; }
  __syncthreads();
  const float tx = r0[0]+r0[1], ty = r1[0]+r1[1], txy = r2[0]+r2[1];
  const float rx = rsqrtf(tx);
  ushort4 o; o.x=f2bf(x.x*rx); o.y=f2bf(x.y*rx); o.z=f2bf(x.z*rx); o.w=f2bf(x.w*rx);
  *reinterpret_cast<ushort4*>(srcb + (size_t)row*DIM + t*4) = o;
  if (t == 0) atomicAdd(S_acc, txy * rsqrtf(tx*ty));
}

// Fused GEMM + per-row running top-10, LDS-FREE.
// Block: 4 waves x 32 rows = 128 rows; grid.y = split of the 3125 col-groups.
// B fragments loaded straight from global (per-lane addresses form whole 64B
// lines; 4 waves/block re-read the same 16KB tile -> L1 serves the reuse).
// 8-deep rotating register prefetch; raw s_barrier only paces waves so both
// blocks' tiles stay inside the 32KB L1 window (no vmcnt(0) drain).
__global__ __launch_bounds__(256) void mm_topk_kernel(const unsigned short* __restrict__ A,
                                                      const unsigned short* __restrict__ Z,
                                                      float* __restrict__ topk){
  const int l = threadIdx.x & 63;
  const int w = threadIdx.x >> 6;
  const int rb = blockIdx.x;
  const int sp = blockIdx.y;
  const int gps = (GTOT + SPLITS - 1)/SPLITS;
  const int g0 = sp*gps;
  const int g1 = min(GTOT, g0 + gps);

  // A frags: lane l holds rows (l&15) and (l&15)+16 of the wave's 32-row tile
  bf16x8 a0[16], a1[16];
  {
    const unsigned short* ap = A + (size_t)(rb*128 + w*32 + (l&15))*DIM + ((l>>4)*8);
    #pragma unroll
    for (int t=0; t<16; ++t){
      a0[t] = *reinterpret_cast<const bf16x8*>(ap + 32*t);
      a1[t] = *reinterpret_cast<const bf16x8*>(ap + 16*DIM + 32*t);
    }
  }

  // per-lane B base: col = l&15 of the group, k-chunk = (l>>4)*8
  const unsigned short* zb = Z + (size_t)(l&15)*DIM + ((l>>4)*8);
  auto LD = [&](int g, int t){
    return *reinterpret_cast<const bf16x8*>(zb + (size_t)g*(16*DIM) + t*32);
  };

  // top-10 lists: lane (l&15)=i holds list[i] (ascending) of row s*16+(l>>4)*4+j
  float lst[2][4], thr[2][4];
  #pragma unroll
  for (int s=0;s<2;++s)
    #pragma unroll
    for (int j=0;j<4;++j){ lst[s][j] = -__builtin_inff(); thr[s][j] = -__builtin_inff(); }

  auto topk_update = [&](f32x4& acc, float* ls, float* th){
    #pragma unroll
    for (int j=0;j<4;++j){
      bool myc = acc[j] > th[j];
      unsigned long long m = __ballot(myc);
      while (m){
        const unsigned long long grp = (m >> (l & 48)) & 0xFFFFull;
        if (grp){ // uniform within the 16-lane group; groups insert concurrently
          const int src = (l & 48) + __builtin_ctzll(grp);
          const float v = __shfl(acc[j], src, 64);
          float nxt = __shfl(ls[j], (l==63)?63:(l+1), 64);
          if ((l & 15) >= 9) nxt = __builtin_inff();
          ls[j] = fminf(nxt, fmaxf(ls[j], v));      // parallel sorted insert-drop-min
          th[j] = __shfl(ls[j], l & 48, 64);        // new 10th-largest
          if (l == src) myc = false;
        }
        m = __ballot(myc);
      }
    }
  };

  // 8-deep rotating prefetch of B fragments
  bf16x8 b[8];
  #pragma unroll
  for (int t=0;t<8;++t) b[t] = LD(g0, t);

  for (int g=g0; g<g1; ++g){
    const int gn = (g+1 < g1) ? g+1 : g0;   // wrap: harmless in-range re-read
    f32x4 acc0 = {0.f,0.f,0.f,0.f};
    f32x4 acc1 = {0.f,0.f,0.f,0.f};
    #pragma unroll
    for (int t=0;t<16;++t){
      bf16x8 cur = b[t & 7];
      b[t & 7] = (t < 8) ? LD(g, t+8) : LD(gn, t-8);   // keep 8 loads in flight
      acc0 = __builtin_amdgcn_mfma_f32_16x16x32_bf16(a0[t], cur, acc0, 0, 0, 0);
      acc1 = __builtin_amdgcn_mfma_f32_16x16x32_bf16(a1[t], cur, acc1, 0, 0, 0);
    }
    topk_update(acc0, lst[0], thr[0]);
    topk_update(acc1, lst[1], thr[1]);
    __builtin_amdgcn_s_barrier();           // pace only: no waitcnt drain
  }

  if ((l & 15) < TOPK){
    #pragma unroll
    for (int s=0;s<2;++s)
      #pragma unroll
      for (int j=0;j<4;++j){
        const int row = rb*128 + w*32 + s*16 + (l>>4)*4 + j;
        topk[((size_t)row*SPLITS + sp)*TOPK + (l & 15)] = lst[s][j];
      }
  }
}

// merge per-split top-10 lists; one thread per (matmul,row); sum top-knn; atomicAdd
__global__ __launch_bounds__(256) void merge_kernel(const float* __restrict__ tk, const int* __restrict__ knnp,
                                                    float* __restrict__ FK){
  const int n = blockIdx.x*256 + threadIdx.x; // 0..8191
  float ls[TOPK];
  #pragma unroll
  for (int i=0;i<TOPK;++i) ls[i] = -__builtin_inff();
  const float* p = tk + (size_t)n*(SPLITS*TOPK);
  for (int i=0;i<SPLITS*TOPK;++i){
    const float v = p[i];
    if (v > ls[0]){
      ls[0] = v;
      #pragma unroll
      for (int k=0;k<TOPK-1;++k){
        if (ls[k] > ls[k+1]){ float tmp=ls[k]; ls[k]=ls[k+1]; ls[k+1]=tmp; }
      }
    }
  }
  const int kk = min(max(knnp[0],1),TOPK);
  float s = 0.f;
  #pragma unroll
  for (int i=0;i<TOPK;++i) if (i < kk) s += ls[TOPK-1-i];
  s = waveSum(s);
  __shared__ float red[4];
  if ((threadIdx.x & 63)==0) red[threadIdx.x>>6] = s;
  __syncthreads();
  if (threadIdx.x==0) atomicAdd(FK, red[0]+red[1]+red[2]+red[3]);
}

__global__ void finalize_kernel(const float* __restrict__ S_acc, const float* __restrict__ FK,
                                const int* __restrict__ knnp, float* __restrict__ out){
  const float k = (float)max(knnp[0],1);
  out[0] = (FK[0]/k - 2.0f*S_acc[0]) / (float)N_ROWS;
}

extern "C" void kernel_launch(void* const* d_in, const int* in_sizes, int n_in,
                              void* d_out, int out_size, void* d_ws, size_t ws_size,
                              hipStream_t stream){
  const float* X  = (const float*)d_in[0];  // X_trans
  const float* Y  = (const float*)d_in[1];  // Y_tgt
  const float* Zs = (const float*)d_in[2];  // Z_src
  const float* Zt = (const float*)d_in[3];  // Z_tgt
  const float* Bk = (const float*)d_in[4];  // back_emb
  const int* knn  = (const int*)d_in[5];

  char* ws = (char*)d_ws;
  float* S_acc = (float*)ws;
  float* FK    = (float*)(ws + 4);
  float* topk0 = (float*)(ws + 64);
  float* topk1 = topk0 + (size_t)N_ROWS*SPLITS*TOPK;
  unsigned short* srcb = (unsigned short*)(ws + 64 + 2*(size_t)N_ROWS*SPLITS*TOPK*4);
  unsigned short* bkb  = srcb + (size_t)N_ROWS*DIM;
  unsigned short* Zb   = bkb  + (size_t)N_ROWS*DIM;   // 50000x512 bf16, reused for Zt then Zs

  hipMemsetAsync(d_ws, 0, 64, stream);                       // zero S/FK accumulators
  dotS_kernel<<<N_ROWS, 128, 0, stream>>>(X, Y, srcb, S_acc);
  norm_bf16_kernel<<<N_ROWS, 128, 0, stream>>>(Bk, bkb);
  norm_bf16_kernel<<<M_COLS, 128, 0, stream>>>(Zt, Zb);
  mm_topk_kernel<<<dim3(N_ROWS/128, SPLITS), 256, 0, stream>>>(srcb, Zb, topk0); // src @ zt^T
  norm_bf16_kernel<<<M_COLS, 128, 0, stream>>>(Zs, Zb);
  mm_topk_kernel<<<dim3(N_ROWS/128, SPLITS), 256, 0, stream>>>(bkb, Zb, topk1);  // bk @ zs^T
  merge_kernel<<<(2*N_ROWS)/256, 256, 0, stream>>>(topk0, knn, FK);
  finalize_kernel<<<1, 1, 0, stream>>>(S_acc, FK, knn, (float*)d_out);
}